// Round 3
// baseline (86.463 us; speedup 1.0000x reference)
//
#include <hip/hip_runtime.h>

// Tree evaluation: N=2048 nodes, node j in [1024,2047] = leaf, [1,1023] = internal.
// Internal j: val = rotate(homog(V[2j], V[2j+1], frac[2048-2j], frac[2047-2j]), theta[j])
// Leaf j:     val = rotate(j%2==0 ? phase1[b] : phase2[b], theta[j])
// Output per batch b: node 1's 6-vector. prop_w/prop_f in the reference are dead code.
//
// Structure: 2 waves per batch element. Each lane evaluates the 15-node subtree
// of one level-7 node in registers; table params come from a lane-interleaved
// stream (all loads coalesced). Then 6 intra-wave shuffle steps reduce to
// node 2/3, one barrier + root op.

#define N_NODES 2048

// D = R^T M R, R = [[a,bb,d],[bb,a,-d],[-d,d,e]], M symmetric (m0 m1 m2; m1 m3 m4; m2 m4 m5)
__device__ __forceinline__ void rotate6(const float* m, float4 r, float* o) {
    float a = r.x, bb = r.y, d = r.z, e = r.w;
    float T00 = m[0]*a  + m[1]*bb - m[2]*d;
    float T01 = m[0]*bb + m[1]*a  + m[2]*d;
    float T02 = (m[0]-m[1])*d + m[2]*e;
    float T10 = m[1]*a  + m[3]*bb - m[4]*d;
    float T11 = m[1]*bb + m[3]*a  + m[4]*d;
    float T12 = (m[1]-m[3])*d + m[4]*e;
    float T20 = m[2]*a  + m[4]*bb - m[5]*d;
    float T21 = m[2]*bb + m[4]*a  + m[5]*d;
    float T22 = (m[2]-m[4])*d + m[5]*e;
    o[0] = a*T00 + bb*T10 - d*T20;
    o[1] = a*T01 + bb*T11 - d*T21;
    o[2] = a*T02 + bb*T12 - d*T22;
    o[3] = bb*T01 + a*T11 + d*T21;
    o[4] = bb*T02 + a*T12 + d*T22;
    o[5] = (T02 - T12)*d + e*T22;
}

__device__ __forceinline__ void homog6(const float* D1, const float* D2,
                                       float f1, float f2, float* o) {
    float gamma = f1*D2[0] + f2*D1[0];
    float g = (gamma == 0.0f) ? 1.0f : gamma;
    float rg = __builtin_amdgcn_rcpf(g);   // threshold 5.7e-2, rcp err ~1ulp: fine
    float ff = f1*f2*rg;
    o[0] = D1[0]*D2[0]*rg;
    o[1] = (f1*D1[1]*D2[0] + f2*D2[1]*D1[0])*rg;
    o[2] = (f1*D1[2]*D2[0] + f2*D2[2]*D1[0])*rg;
    float t1 = D1[1]-D2[1];
    float t2 = D1[2]-D2[2];
    o[3] = f1*D1[3] + f2*D2[3] - ff*t1*t1;
    o[4] = f1*D1[4] + f2*D2[4] - ff*t2*t1;
    o[5] = f1*D1[5] + f2*D2[5] - ff*t2*t2;
}

// Stream layout (p = j7 position 0..127, j7 = 128+p):
// rotS[op*128+p], op: 0:8j7 1:8j7+1 2:4j7 | 3:8j7+2 4:8j7+3 5:4j7+1 | 6:2j7 |
//                     7:8j7+4 8:8j7+5 9:4j7+2 | 10:8j7+6 11:8j7+7 12:4j7+3 | 13:2j7+1 | 14:j7
// frS[op*128+p],  op: 0:4j7 1:4j7+1 2:2j7 3:4j7+2 4:4j7+3 5:2j7+1 6:j7

__device__ __forceinline__ void subtree9_s(const float* p1, const float* p2,
                                           const float4* __restrict__ rotS,
                                           const float2* __restrict__ frS,
                                           int p, int ro, int fo, float* outD) {
    float L[6], R[6], H[6];
    rotate6(p1, rotS[(ro+0)*128 + p], L);   // even leaf -> phase1
    rotate6(p2, rotS[(ro+1)*128 + p], R);   // odd leaf  -> phase2
    float2 f = frS[fo*128 + p];
    homog6(L, R, f.x, f.y, H);
    rotate6(H, rotS[(ro+2)*128 + p], outD);
}

__device__ __forceinline__ float4 mk_rot(float t) {
    float c = cosf(t), s = sinf(t);
    float a = c*c, bb = s*s;
    float d = sqrtf(2.0f) * c * s;
    return make_float4(a, bb, d, a - bb);
}

__device__ __forceinline__ float2 mk_fr(const float* fractions, int j) {
    return make_float2(fractions[N_NODES - 2*j], fractions[N_NODES - 2*j - 1]);
}

__global__ void setup_kernel(const float* __restrict__ theta,
                             const float* __restrict__ fractions,
                             float4* __restrict__ rot, float2* __restrict__ fr,
                             float4* __restrict__ rotS, float2* __restrict__ frS) {
    int gid = blockIdx.x * blockDim.x + threadIdx.x;
    if (gid < N_NODES) {
        // plain tables (used by the shuffle phase; j<1024 would suffice but cheap)
        int j = gid;
        if (j >= 1) rot[j] = mk_rot(theta[j]);
        if (j >= 1 && j < N_NODES/2) fr[j] = mk_fr(fractions, j);
    } else {
        // lane-interleaved stream for the register phase
        int p = gid - N_NODES;
        if (p < 128) {
            int j7 = 128 + p;
            const int rops[15] = {8*j7, 8*j7+1, 4*j7,  8*j7+2, 8*j7+3, 4*j7+1,  2*j7,
                                  8*j7+4, 8*j7+5, 4*j7+2,  8*j7+6, 8*j7+7, 4*j7+3,  2*j7+1,  j7};
            const int fops[7]  = {4*j7, 4*j7+1, 2*j7, 4*j7+2, 4*j7+3, 2*j7+1, j7};
#pragma unroll
            for (int op = 0; op < 15; ++op) rotS[op*128 + p] = mk_rot(theta[rops[op]]);
#pragma unroll
            for (int op = 0; op < 7; ++op)  frS[op*128 + p]  = mk_fr(fractions, fops[op]);
        }
    }
}

__global__ __launch_bounds__(256) void tree_kernel(
    const float* __restrict__ phase1, const float* __restrict__ phase2,
    const float4* __restrict__ rot, const float2* __restrict__ fr,
    const float4* __restrict__ rotS, const float2* __restrict__ frS,
    float* __restrict__ out)
{
    const int tid  = threadIdx.x;
    const int wid  = tid >> 6;      // 0..3
    const int lane = tid & 63;
    const int half = wid & 1;       // which half of this batch's level-7 nodes
    const int bloc = wid >> 1;      // batch slot within block (0 or 1)
    const int b    = blockIdx.x * 2 + bloc;

    float p1[6], p2[6];
#pragma unroll
    for (int k = 0; k < 6; ++k) { p1[k] = phase1[b*6+k]; p2[k] = phase2[b*6+k]; }

    // Register phase: this lane's level-7 node, all table loads coalesced.
    float A[6], Bv[6], H[6], v[6];
    {
        const int p = half*64 + lane;
        float DA[6], DB[6];
        subtree9_s(p1, p2, rotS, frS, p, 0, 0, DA);
        subtree9_s(p1, p2, rotS, frS, p, 3, 1, DB);
        float2 f = frS[2*128 + p];
        homog6(DA, DB, f.x, f.y, H);
        rotate6(H, rotS[6*128 + p], A);

        subtree9_s(p1, p2, rotS, frS, p, 7, 3, DA);
        subtree9_s(p1, p2, rotS, frS, p, 10, 4, DB);
        f = frS[5*128 + p];
        homog6(DA, DB, f.x, f.y, H);
        rotate6(H, rotS[13*128 + p], Bv);

        f = frS[6*128 + p];
        homog6(A, Bv, f.x, f.y, H);
        rotate6(H, rotS[14*128 + p], v);
    }

    // Intra-wave shuffle reduction: 6 levels, no barriers.
    // half=0 holds nodes [128,192) -> node 2; half=1 [192,256) -> node 3.
    int jbase = 128 + half*64;
    int width = 64;
#pragma unroll
    for (int s = 0; s < 6; ++s) {
        float ce[6], co[6];
#pragma unroll
        for (int k = 0; k < 6; ++k) {
            ce[k] = __shfl(v[k], 2*lane,     64);
            co[k] = __shfl(v[k], 2*lane + 1, 64);
        }
        jbase >>= 1;
        width >>= 1;
        if (lane < width) {
            int j = jbase + lane;            // contiguous -> coalesced table loads
            float2 f = fr[j];
            homog6(ce, co, f.x, f.y, H);
            rotate6(H, rot[j], v);
        }
    }

    // Combine node 2 / node 3 across the wave pair; root op by 2 threads.
    __shared__ float comb[2][2][6];   // [batch slot][node-2/3][component]
    if (lane == 0) {
#pragma unroll
        for (int k = 0; k < 6; ++k) comb[bloc][half][k] = v[k];
    }
    __syncthreads();

    if (tid < 2) {
        float D1[6], D2[6], Hh[6], Dn[6];
#pragma unroll
        for (int k = 0; k < 6; ++k) { D1[k] = comb[tid][0][k]; D2[k] = comb[tid][1][k]; }
        float2 f = fr[1];
        homog6(D1, D2, f.x, f.y, Hh);
        rotate6(Hh, rot[1], Dn);
        int bb = blockIdx.x * 2 + tid;
#pragma unroll
        for (int k = 0; k < 6; ++k) out[bb*6 + k] = Dn[k];
    }
}

extern "C" void kernel_launch(void* const* d_in, const int* in_sizes, int n_in,
                              void* d_out, int out_size, void* d_ws, size_t ws_size,
                              hipStream_t stream) {
    const float* phase1    = (const float*)d_in[0];
    const float* phase2    = (const float*)d_in[1];
    const float* theta     = (const float*)d_in[2];
    // d_in[3] activation, d_in[4] weight, d_in[6] left, d_in[7] right: dead code / fixed tree
    const float* fractions = (const float*)d_in[5];
    float* out = (float*)d_out;

    const int B = in_sizes[0] / 6;

    char* ws = (char*)d_ws;
    float4* rot  = (float4*)ws;                      ws += N_NODES * sizeof(float4);   // 32 KB
    float2* fr   = (float2*)ws;                      ws += (N_NODES/2) * sizeof(float2); // 8 KB
    float4* rotS = (float4*)ws;                      ws += 15 * 128 * sizeof(float4);  // 30 KB
    float2* frS  = (float2*)ws;                                                        // 7 KB

    // blocks 0..7: plain tables; block 8: interleaved stream (independent, read-only inputs)
    hipLaunchKernelGGL(setup_kernel, dim3((N_NODES + 128 + 255) / 256), dim3(256), 0, stream,
                       theta, fractions, rot, fr, rotS, frS);
    hipLaunchKernelGGL(tree_kernel, dim3(B / 2), dim3(256), 0, stream,
                       phase1, phase2, rot, fr, rotS, frS, out);
}

// Round 4
// 83.154 us; speedup vs baseline: 1.0398x; 1.0398x over previous
//
#include <hip/hip_runtime.h>

// Tree evaluation: N=2048 nodes, node j in [1024,2047] = leaf, [1,1023] = internal.
// Internal j: val = rotate(homog(V[2j], V[2j+1], frac[2048-2j], frac[2047-2j]), theta[j])
// Leaf j:     val = rotate(j%2==0 ? phase1[b] : phase2[b], theta[j])
// Output per batch b: node 1's 6-vector. prop_w/prop_f in the reference are dead code.
//
// Structure: ONE wave per batch element, zero barriers, zero LDS.
// Lane l evaluates the 31-node subtree rooted at level-6 node j6=64+l entirely
// in registers (params from a lane-interleaved stream, all loads coalesced),
// then 6 intra-wave shuffle levels reduce 64 level-6 values -> node 1.

#define N_NODES 2048

// D = R^T M R, R = [[a,bb,d],[bb,a,-d],[-d,d,e]], M symmetric (m0 m1 m2; m1 m3 m4; m2 m4 m5)
__device__ __forceinline__ void rotate6(const float* m, float4 r, float* o) {
    float a = r.x, bb = r.y, d = r.z, e = r.w;
    float T00 = m[0]*a  + m[1]*bb - m[2]*d;
    float T01 = m[0]*bb + m[1]*a  + m[2]*d;
    float T02 = (m[0]-m[1])*d + m[2]*e;
    float T10 = m[1]*a  + m[3]*bb - m[4]*d;
    float T11 = m[1]*bb + m[3]*a  + m[4]*d;
    float T12 = (m[1]-m[3])*d + m[4]*e;
    float T20 = m[2]*a  + m[4]*bb - m[5]*d;
    float T21 = m[2]*bb + m[4]*a  + m[5]*d;
    float T22 = (m[2]-m[4])*d + m[5]*e;
    o[0] = a*T00 + bb*T10 - d*T20;
    o[1] = a*T01 + bb*T11 - d*T21;
    o[2] = a*T02 + bb*T12 - d*T22;
    o[3] = bb*T01 + a*T11 + d*T21;
    o[4] = bb*T02 + a*T12 + d*T22;
    o[5] = (T02 - T12)*d + e*T22;
}

__device__ __forceinline__ void homog6(const float* D1, const float* D2,
                                       float f1, float f2, float* o) {
    float gamma = f1*D2[0] + f2*D1[0];
    float g = (gamma == 0.0f) ? 1.0f : gamma;
    float rg = __builtin_amdgcn_rcpf(g);   // threshold 5.7e-2; ~1ulp rcp is fine
    float ff = f1*f2*rg;
    o[0] = D1[0]*D2[0]*rg;
    o[1] = (f1*D1[1]*D2[0] + f2*D2[1]*D1[0])*rg;
    o[2] = (f1*D1[2]*D2[0] + f2*D2[2]*D1[0])*rg;
    float t1 = D1[1]-D2[1];
    float t2 = D1[2]-D2[2];
    o[3] = f1*D1[3] + f2*D2[3] - ff*t1*t1;
    o[4] = f1*D1[4] + f2*D2[4] - ff*t2*t1;
    o[5] = f1*D1[5] + f2*D2[5] - ff*t2*t2;
}

__device__ __forceinline__ float4 mk_rot(float t) {
    float c = cosf(t), s = sinf(t);
    float a = c*c, bb = s*s;
    float d = sqrtf(2.0f) * c * s;
    return make_float4(a, bb, d, a - bb);
}

__device__ __forceinline__ float2 mk_fr(const float* __restrict__ fractions, int j) {
    return make_float2(fractions[N_NODES - 2*j], fractions[N_NODES - 2*j - 1]);
}

// DFS op -> node mapping for the register phase: node = M*j6 + C.
// Order mirrors the template expansion below (sub9 emits rot(2j9),rot(2j9+1),rot(j9)).
__constant__ int RM[31] = {16,16,8, 16,16,8, 4, 16,16,8, 16,16,8, 4, 2,
                           16,16,8, 16,16,8, 4, 16,16,8, 16,16,8, 4, 2, 1};
__constant__ int RC[31] = {0,1,0, 2,3,1, 0, 4,5,2, 6,7,3, 1, 0,
                           8,9,4, 10,11,5, 2, 12,13,6, 14,15,7, 3, 1, 0};
__constant__ int FM[15] = {8,8,4, 8,8,4, 2, 8,8,4, 8,8,4, 2, 1};
__constant__ int FC[15] = {0,1,0, 2,3,1, 0, 4,5,2, 6,7,3, 1, 0};

__global__ void setup_kernel(const float* __restrict__ theta,
                             const float* __restrict__ fractions,
                             float4* __restrict__ rot, float2* __restrict__ fr,
                             float4* __restrict__ rotS, float2* __restrict__ frS) {
    int gid = blockIdx.x * blockDim.x + threadIdx.x;
    if (gid < 64*31) {                       // register-phase rot stream
        int p = gid & 63, op = gid >> 6;
        int j6 = 64 + p;
        rotS[op*64 + p] = mk_rot(theta[RM[op]*j6 + RC[op]]);
    } else if (gid < 64*31 + 64*15) {        // register-phase fr stream
        int t = gid - 64*31;
        int p = t & 63, op = t >> 6;
        int j6 = 64 + p;
        frS[op*64 + p] = mk_fr(fractions, FM[op]*j6 + FC[op]);
    } else {                                 // plain tables for shuffle phase, j in [1,64)
        int j = gid - (64*31 + 64*15);
        if (j >= 1 && j < 64) {
            rot[j] = mk_rot(theta[j]);
            fr[j]  = mk_fr(fractions, j);
        }
    }
}

// ---- register-phase subtree evaluation, compile-time stream offsets ----
template<int RO, int FO>
__device__ __forceinline__ void sub9(const float* p1, const float* p2,
                                     const float4* __restrict__ rotS,
                                     const float2* __restrict__ frS,
                                     int lane, float* outD) {
    float L[6], R[6], H[6];
    rotate6(p1, rotS[(RO+0)*64 + lane], L);   // even leaf -> phase1
    rotate6(p2, rotS[(RO+1)*64 + lane], R);   // odd leaf  -> phase2
    float2 f = frS[FO*64 + lane];
    homog6(L, R, f.x, f.y, H);
    rotate6(H, rotS[(RO+2)*64 + lane], outD);
}

template<int RO, int FO>
__device__ __forceinline__ void node8(const float* p1, const float* p2,
                                      const float4* __restrict__ rotS,
                                      const float2* __restrict__ frS,
                                      int lane, float* outD) {
    float A[6], B[6], H[6];
    sub9<RO,   FO  >(p1, p2, rotS, frS, lane, A);
    sub9<RO+3, FO+1>(p1, p2, rotS, frS, lane, B);
    float2 f = frS[(FO+2)*64 + lane];
    homog6(A, B, f.x, f.y, H);
    rotate6(H, rotS[(RO+6)*64 + lane], outD);
}

template<int RO, int FO>
__device__ __forceinline__ void node7(const float* p1, const float* p2,
                                      const float4* __restrict__ rotS,
                                      const float2* __restrict__ frS,
                                      int lane, float* outD) {
    float A[6], B[6], H[6];
    node8<RO,   FO  >(p1, p2, rotS, frS, lane, A);
    node8<RO+7, FO+3>(p1, p2, rotS, frS, lane, B);
    float2 f = frS[(FO+6)*64 + lane];
    homog6(A, B, f.x, f.y, H);
    rotate6(H, rotS[(RO+14)*64 + lane], outD);
}

__global__ __launch_bounds__(256) void tree_kernel(
    const float* __restrict__ phase1, const float* __restrict__ phase2,
    const float4* __restrict__ rot, const float2* __restrict__ fr,
    const float4* __restrict__ rotS, const float2* __restrict__ frS,
    float* __restrict__ out)
{
    const int tid  = threadIdx.x;
    const int wid  = tid >> 6;            // wave within block = batch slot
    const int lane = tid & 63;
    const int b    = blockIdx.x * 4 + wid;

    float p1[6], p2[6];
#pragma unroll
    for (int k = 0; k < 6; ++k) { p1[k] = phase1[b*6+k]; p2[k] = phase2[b*6+k]; }

    // Register phase: lane's level-6 node j6 = 64+lane, 31 node-ops, no LDS.
    float A[6], Bv[6], H[6], v[6];
    node7<0,  0>(p1, p2, rotS, frS, lane, A);
    node7<15, 7>(p1, p2, rotS, frS, lane, Bv);
    {
        float2 f = frS[14*64 + lane];
        homog6(A, Bv, f.x, f.y, H);
        rotate6(H, rotS[30*64 + lane], v);
    }

    // Shuffle phase: 6 levels, wave-private, no barriers. Lanes hold nodes [64,128).
    int jbase = 64;
    int width = 64;
#pragma unroll
    for (int s = 0; s < 6; ++s) {
        float ce[6], co[6];
#pragma unroll
        for (int k = 0; k < 6; ++k) {
            ce[k] = __shfl(v[k], 2*lane,     64);
            co[k] = __shfl(v[k], 2*lane + 1, 64);
        }
        jbase >>= 1;
        width >>= 1;
        if (lane < width) {
            int j = jbase + lane;              // contiguous -> coalesced table loads
            float2 f = fr[j];
            homog6(ce, co, f.x, f.y, H);
            rotate6(H, rot[j], v);
        }
    }

    // Lane 0 holds node 1 = the output for batch b.
    if (lane == 0) {
#pragma unroll
        for (int k = 0; k < 6; ++k) out[b*6 + k] = v[k];
    }
}

extern "C" void kernel_launch(void* const* d_in, const int* in_sizes, int n_in,
                              void* d_out, int out_size, void* d_ws, size_t ws_size,
                              hipStream_t stream) {
    const float* phase1    = (const float*)d_in[0];
    const float* phase2    = (const float*)d_in[1];
    const float* theta     = (const float*)d_in[2];
    // d_in[3] activation, d_in[4] weight, d_in[6] left, d_in[7] right: dead code / fixed tree
    const float* fractions = (const float*)d_in[5];
    float* out = (float*)d_out;

    const int B = in_sizes[0] / 6;

    char* ws = (char*)d_ws;
    float4* rotS = (float4*)ws;  ws += 31*64*sizeof(float4);  // 31744 B
    float2* frS  = (float2*)ws;  ws += 15*64*sizeof(float2);  //  7680 B
    float4* rot  = (float4*)ws;  ws += 64*sizeof(float4);     //  1024 B
    float2* fr   = (float2*)ws;                               //   512 B

    const int setup_threads = 64*31 + 64*15 + 64;             // 3008
    hipLaunchKernelGGL(setup_kernel, dim3((setup_threads + 255)/256), dim3(256), 0, stream,
                       theta, fractions, rot, fr, rotS, frS);
    hipLaunchKernelGGL(tree_kernel, dim3(B / 4), dim3(256), 0, stream,
                       phase1, phase2, rot, fr, rotS, frS, out);
}